// Round 9
// baseline (3675.182 us; speedup 1.0000x reference)
//
#include <hip/hip_runtime.h>

#define Tn 1024
#define Bn 64
#define In_ 64
#define Hn 512
#define On 64
#define DTC 0.5f

typedef __attribute__((ext_vector_type(8))) short short8;   // bf16x8 MFMA frag
typedef __attribute__((ext_vector_type(4))) float floatx4;  // MFMA C frag
typedef unsigned long long u64;

__device__ __forceinline__ float bf2f(unsigned short u){
  union{unsigned int i; float f;} v; v.i = ((unsigned int)u)<<16; return v.f;
}
__device__ __forceinline__ unsigned short f2bf(float f){   // RNE
  union{float f; unsigned int i;} v; v.f=f;
  unsigned int x=v.i;
  return (unsigned short)((x + 0x7fffu + ((x>>16)&1u))>>16);
}
__device__ __forceinline__ short8 cvt8(const float* p){
  short8 v;
  #pragma unroll
  for (int e=0;e<8;e++) v[e] = (short)f2bf(p[e]);
  return v;
}
__device__ __forceinline__ unsigned int cvtpk_bf16(float a, float b){
  unsigned int r;  // dst.lo = bf16(a), dst.hi = bf16(b), RNE
  asm("v_cvt_pk_bf16_f32 %0, %1, %2" : "=v"(r) : "v"(a), "v"(b));
  return r;
}
__device__ __forceinline__ float fast_rcp(float x){         // v_rcp_f32
  float r; asm("v_rcp_f32 %0, %1" : "=v"(r) : "v"(x)); return r;
}
// raw LDS-only barrier: no vmcnt(0) drain — global loads/stores keep flying
// across it (this is what makes cross-step VMEM prefetch legal and useful).
__device__ __forceinline__ void barrier_lds(){
  asm volatile("s_waitcnt lgkmcnt(0)\n\ts_barrier" ::: "memory");
}

// ---------------- xproj: xp[t][b][j] = inp[b][t][:]@wi[:,j] + brec[j] (bf16) --------
__global__ __launch_bounds__(256,2) void xproj_kernel(
    const float* __restrict__ inp, const float* __restrict__ wi,
    const float* __restrict__ brec, unsigned short* __restrict__ xp)
{
  const int t = blockIdx.x, tid = threadIdx.x;
  const int wv = tid>>6, lane = tid&63, col = lane&15, quad = lane>>4;
  __shared__ __align__(16) unsigned short inA[64*80];   // [b][i], pad 80
  {
    int r = tid>>2, i0 = (tid&3)*16;
    const float* src = inp + ((size_t)r*Tn + t)*In_ + i0;
    unsigned short tmp[16];
    #pragma unroll
    for (int q=0;q<16;q++) tmp[q] = f2bf(src[q]);
    *(short8*)&inA[r*80 + i0]     = *(short8*)&tmp[0];
    *(short8*)&inA[r*80 + i0 + 8] = *(short8*)&tmp[8];
  }
  const int wnb = wv*128;
  short8 bw[8][2];
  float brecv[8];
  #pragma unroll
  for (int nt=0;nt<8;nt++){
    int j = wnb + nt*16 + col;
    brecv[nt] = brec[j];
    #pragma unroll
    for (int ks=0;ks<2;ks++){
      float tmp[8];
      #pragma unroll
      for (int e=0;e<8;e++) tmp[e] = wi[(size_t)(ks*32 + quad*8 + e)*Hn + j];
      bw[nt][ks] = cvt8(tmp);
    }
  }
  __syncthreads();
  floatx4 acc[4][8];
  #pragma unroll
  for (int mt=0;mt<4;mt++)
    #pragma unroll
    for (int nt=0;nt<8;nt++) acc[mt][nt] = (floatx4){0.f,0.f,0.f,0.f};
  #pragma unroll
  for (int ks=0;ks<2;ks++)
    #pragma unroll
    for (int mt=0;mt<4;mt++){
      short8 ar = *(const short8*)&inA[(mt*16+col)*80 + ks*32 + quad*8];
      #pragma unroll
      for (int nt=0;nt<8;nt++)
        acc[mt][nt] = __builtin_amdgcn_mfma_f32_16x16x32_bf16(ar, bw[nt][ks], acc[mt][nt],0,0,0);
    }
  #pragma unroll
  for (int mt=0;mt<4;mt++)
    #pragma unroll
    for (int nt=0;nt<8;nt++)
      #pragma unroll
      for (int r=0;r<4;r++){
        int b = mt*16 + quad*4 + r;
        int j = wnb + nt*16 + col;
        xp[((size_t)t*Bn + b)*Hn + j] = f2bf(acc[mt][nt][r] + brecv[nt]);
      }
}

// ------------- wrec_pack: bf16 A-frags, layout [ks][jt] (512KB) ---------------------
// frag fi = ks*32+jt (ks=k-slice 0..15, jt=j-tile 0..31); lane l holds
// wrec[jt*16 + (l&15)][ks*32 + (l>>4)*8 + e], e=0..7  -> wrecB[(fi*64+l)*8 + e]
__global__ __launch_bounds__(256,1) void wrec_pack(
    const float* __restrict__ wrec, unsigned short* __restrict__ wrecB)
{
  int gl = blockIdx.x*256 + threadIdx.x;      // 0..32767
  int fi = gl>>6, lane = gl&63;
  int ks = fi>>5, jt = fi&31;
  int j = jt*16 + (lane&15);
  int k = ks*32 + (lane>>4)*8;
  short8 v = cvt8(wrec + (size_t)j*Hn + k);
  *(short8*)(wrecB + (size_t)gl*8) = v;
}

// ------------- scan: 4 blocks x 512 threads (8 waves = 2/SIMD) ----------------------
// pre^T[j][b] = sum_k wrec[j][k] h[b][k].  Wave wv owns j in [64wv,64wv+64) (mt=0..3).
// r7's proven lever extended: wrec is STEP-INVARIANT + barrier_lds doesn't drain
// vmcnt -> ALL streamed A traffic gets long lead (cross-step or >=7 blocks) and
// lives on the hideable VMEM pipe.  r8's anti-align reverted (neutral).
// NEW slice plan shifts A weight off the LDS pipe (the 1:1 read:MFMA offender):
//   ks 0..5      -> reg (accum 96 + acc 16 = 112)
//   ks 6,7,15    -> LDS wrecL (96KB persistent)       LDS/CU ~2880cy (was 3264)
//   ks 8..14     -> streamed L2: 8,9 cross-step persistent; 10..12 step-top;
//                   13,14 reloaded mid-sweep (7-block ~550cy lead)
// Arch regs hand-counted ~140 of 144.  hA dbuf 32KB -> one LDS barrier/step.
// LDS total 128KB.  No sched_barrier/setprio: compiler schedules.
__global__ __launch_bounds__(512,2) void rnn_scan(
    const float* __restrict__ h0,
    const unsigned short* xp,            // ws+64KB  [T][B][H] bf16 (aliases hs+1 slot)
    const unsigned short* __restrict__ wrecB,
    unsigned short* hs)                  // ws       [T][B][H] bf16
{
  const int tid  = threadIdx.x;
  const int g    = blockIdx.x;          // batch group: b in [16g, 16g+16)
  const int wv   = tid >> 6;            // 0..7
  const int lane = tid & 63;
  const int col  = lane & 15;
  const int quad = lane >> 4;
  const int wbase = wv*64;

  __shared__ __align__(16) unsigned short wrecL[3*32*512]; // 96KB: slices 6,7,15
  __shared__ __align__(16) unsigned short hA[2*8192];      // 32KB: h frags, dbuf

  // frag (ks, jt=wv*4+mt) lives at wrecB[((ks*32 + wv*4 + mt)*64 + lane)*8]
  const unsigned short* pw = wrecB + ((size_t)(wv*4)*64 + lane)*8;
  #define WOFF(ks,mt) ((size_t)((ks)*32 + (mt))*512)

  // A-frags ks 0..5, register-resident (accum side)
  short8 awr[4][6];
  #pragma unroll
  for (int mt=0;mt<4;mt++)
    #pragma unroll
    for (int ks=0;ks<6;ks++)
      awr[mt][ks] = *(const short8*)(pw + WOFF(ks,mt));

  // A-frags ks 6,7,15 -> LDS; frag (jt=wv*4+mt, s) at ((wv*4+mt)*3+s)*512 shorts
  #pragma unroll
  for (int s=0;s<3;s++){
    const int ksrc = (s==2) ? 15 : (6+s);
    #pragma unroll
    for (int mt=0;mt<4;mt++)
      *(short8*)&wrecL[((wv*4+mt)*3+s)*512 + lane*8] =
          *(const short8*)(pw + WOFF(ksrc,mt));
  }
  const unsigned short* wl = wrecL + (wv*12)*512 + lane*8;  // + (mt*3+s)*512 imm

  // h0 -> hA buffer 0 (frag layout: (b,k) at ((k>>5)*64+((k>>3)&3)*16+b)*8+(k&7))
  for (int idx = tid; idx < 16*Hn; idx += 512){
    int b = idx >> 9, k = idx & 511;
    hA[(((k>>5)*64 + ((k>>3)&3)*16 + b))*8 + (k&7)] = f2bf(h0[k]);
  }
  // fp32 h master: lane owns (b=col, j = wbase+mt*16+quad*4+r)
  float hm[4][4];
  #pragma unroll
  for (int mt=0;mt<4;mt++)
    #pragma unroll
    for (int r=0;r<4;r++) hm[mt][r] = h0[wbase + mt*16 + quad*4 + r];

  floatx4 acc[4];
  #pragma unroll
  for (int mt=0;mt<4;mt++) acc[mt] = (floatx4){0.f,0.f,0.f,0.f};

  // loop-invariant offsets
  const int row = g*16 + col;           // global batch for this lane
  int xoff[4], woff[4];
  #pragma unroll
  for (int mt=0;mt<4;mt++){
    int j4 = wbase + mt*16 + quad*4;
    xoff[mt] = row*Hn + j4;
    woff[mt] = (((j4>>5)*64 + ((j4>>3)&3)*16 + col))*8 + (j4&7);
  }
  const unsigned short* xq = xp;        // uniform, bumped per step (SGPR)
  unsigned short* hq = hs;
  int hoff = 0;

  __syncthreads();

  #define MFMA4R(KS, HB) { \
    _Pragma("unroll") \
    for (int mt=0;mt<4;mt++) \
      acc[mt] = __builtin_amdgcn_mfma_f32_16x16x32_bf16(awr[mt][KS], (HB), acc[mt],0,0,0); }
  #define MFMA4W(W, HB) { \
    _Pragma("unroll") \
    for (int mt=0;mt<4;mt++) \
      acc[mt] = __builtin_amdgcn_mfma_f32_16x16x32_bf16((W)[mt], (HB), acc[mt],0,0,0); }
  #define MFMA4L(S, HB) { \
    _Pragma("unroll") \
    for (int mt=0;mt<4;mt++){ \
      short8 aw = *(const short8*)(wl + (mt*3+(S))*512); \
      acc[mt] = __builtin_amdgcn_mfma_f32_16x16x32_bf16(aw, (HB), acc[mt],0,0,0); } }
  #define LOADW(W, KS) { \
    _Pragma("unroll") \
    for (int mt=0;mt<4;mt++) (W)[mt] = *(const short8*)(pw + WOFF(KS,mt)); }
  #define RDHB(S) (*(const short8*)(hc + (S)*512))

  // cross-step prefetch of streamed slices 8,9 (wrec is step-invariant)
  short8 wstP0[4], wstP1[4], wstA[4], wstB[4], wstC[4];
  LOADW(wstP0, 8); LOADW(wstP1, 9);

  for (int t = 0; t < Tn; t++){
    // step-top: xproj loads (consumed in epilogue) + streams 10,11,12
    u64 xv[4];
    #pragma unroll
    for (int mt=0;mt<4;mt++) xv[mt] = *(const u64*)(xq + xoff[mt]);
    LOADW(wstA, 10); LOADW(wstB, 11); LOADW(wstC, 12);

    const unsigned short* hc = hA + hoff + lane*8;

    // B0..B5: reg slices 0..5 (covers L2 latency of step-top loads)
    #pragma unroll
    for (int ks=0;ks<6;ks++){
      short8 hb = RDHB(ks);
      MFMA4R(ks, hb);
    }
    { short8 hb = RDHB(10); MFMA4W(wstA, hb); }  LOADW(wstA, 13);  // B6:  ks10
    { short8 hb = RDHB(11); MFMA4W(wstB, hb); }  LOADW(wstB, 14);  // B7:  ks11
    { short8 hb = RDHB(8);  MFMA4W(wstP0,hb); }  LOADW(wstP0, 8);  // B8:  ks8 ->t+1
    { short8 hb = RDHB(9);  MFMA4W(wstP1,hb); }  LOADW(wstP1, 9);  // B9:  ks9 ->t+1
    { short8 hb = RDHB(6);  MFMA4L(0, hb); }                       // B10: ks6 (LDS)
    { short8 hb = RDHB(12); MFMA4W(wstC, hb); }                    // B11: ks12
    { short8 hb = RDHB(7);  MFMA4L(1, hb); }                       // B12: ks7 (LDS)
    { short8 hb = RDHB(13); MFMA4W(wstA, hb); }                    // B13: ks13
    { short8 hb = RDHB(14); MFMA4W(wstB, hb); }                    // B14: ks14
    { short8 hb = RDHB(15); MFMA4L(2, hb); }                       // B15: ks15 (LDS)

    // epilogue: writes go to the OTHER hA buffer -> no pre-barrier needed.
    // tanh(pre) = 1 - 2/(e^{2pre}+1); hn = fma(.5,hm,.5) - rcp(e+1)
    unsigned short* hw = hA + (hoff ^ 8192);
    #pragma unroll
    for (int mt=0;mt<4;mt++){
      u64 x = xv[mt];
      float hn[4];
      #pragma unroll
      for (int r=0;r<4;r++){
        float pre = acc[mt][r] + bf2f((unsigned short)(x >> (16*r)));
        float e   = __expf(2.0f*pre);                  // v_mul + v_exp
        float rc  = fast_rcp(e + 1.0f);                // v_add + v_rcp
        float v   = __builtin_fmaf(0.5f, hm[mt][r], 0.5f) - rc;
        hm[mt][r] = v;
        hn[r] = v;
      }
      unsigned int lo = cvtpk_bf16(hn[0], hn[1]);
      unsigned int hi = cvtpk_bf16(hn[2], hn[3]);
      uint2 w; w.x = lo; w.y = hi;
      *(uint2*)&hw[woff[mt]] = w;                      // ds_write_b64, frag layout
      u64 pk = (u64)lo | ((u64)hi << 32);
      __builtin_nontemporal_store(pk, (u64*)(hq + xoff[mt]));   // hs[t][b][j4..j4+3]
      acc[mt] = (floatx4){0.f,0.f,0.f,0.f};
    }
    barrier_lds();     // LDS ops drained CU-wide; prefetched VMEM keeps flying
    hoff ^= 8192;
    xq += Bn*Hn;
    hq += Bn*Hn;
  }
  #undef MFMA4R
  #undef MFMA4W
  #undef MFMA4L
  #undef LOADW
  #undef RDHB
  #undef WOFF
}

// ------------- out: out[b][t][o] = hs[t][b][:] @ wo ; rows m = t*64+b ---------------
__global__ __launch_bounds__(256,1) void out_gemm(
    const unsigned short* __restrict__ hs,
    const float* __restrict__ wo,
    float* __restrict__ out)
{
  const int tid = threadIdx.x, bid = blockIdx.x;
  const int wv = tid >> 6, lane = tid & 63, col = lane & 15, quad = lane >> 4;
  const int m0 = bid*64;
  __shared__ __align__(16) unsigned short hsA[64][520];

  for (int c = tid; c < 64*64; c += 256){
    int r = c >> 6, cc = (c & 63)*8;
    *(short8*)&hsA[r][cc] = *(const short8*)(hs + (size_t)(m0 + r)*Hn + cc);
  }
  short8 boh[16], bol[16];
  #pragma unroll
  for (int kk = 0; kk < 16; kk++){
    float tmp[8];
    #pragma unroll
    for (int e = 0; e < 8; e++) tmp[e] = wo[(size_t)(kk*32 + quad*8 + e)*On + wv*16 + col];
    #pragma unroll
    for (int e = 0; e < 8; e++){
      unsigned short h = f2bf(tmp[e]);
      boh[kk][e] = (short)h;
      bol[kk][e] = (short)f2bf(tmp[e] - bf2f(h));
    }
  }
  __syncthreads();

  floatx4 acc[4];
  #pragma unroll
  for (int ms=0;ms<4;ms++) acc[ms] = (floatx4){0.f,0.f,0.f,0.f};
  #pragma unroll
  for (int kk = 0; kk < 16; kk++){
    int k = kk*32 + quad*8;
    #pragma unroll
    for (int ms = 0; ms < 4; ms++){
      short8 a = *(const short8*)&hsA[ms*16 + col][k];
      acc[ms] = __builtin_amdgcn_mfma_f32_16x16x32_bf16(a, boh[kk], acc[ms], 0,0,0);
      acc[ms] = __builtin_amdgcn_mfma_f32_16x16x32_bf16(a, bol[kk], acc[ms], 0,0,0);
    }
  }
  #pragma unroll
  for (int ms = 0; ms < 4; ms++)
    #pragma unroll
    for (int r = 0; r < 4; r++){
      int m = m0 + ms*16 + quad*4 + r;     // m = t*64 + b
      int b = m & 63, tt = m >> 6;
      out[((size_t)b*Tn + tt)*On + wv*16 + col] = acc[ms][r];
    }
}

extern "C" void kernel_launch(void* const* d_in, const int* in_sizes, int n_in,
                              void* d_out, int out_size, void* d_ws, size_t ws_size,
                              hipStream_t stream){
  const float* inp  = (const float*)d_in[0];
  const float* wi   = (const float*)d_in[1];
  const float* wrec = (const float*)d_in[2];
  const float* wo   = (const float*)d_in[3];
  const float* brec = (const float*)d_in[4];
  const float* h0   = (const float*)d_in[5];
  float* out = (float*)d_out;

  char* ws = (char*)d_ws;
  // hs slots: ws + t*64KB. xp slots: ws + 64KB + t*64KB (= hs slot t+1).
  // Scan step t writes hs[t] (destroys xp[t-1], already consumed; per-group
  // b-slices disjoint, so cross-block skew is safe). wrecB (512KB packed
  // bf16 frags, [ks][jt] order) lives past the last xp slot.
  unsigned short* hs = (unsigned short*)ws;
  unsigned short* xp = (unsigned short*)(ws + 65536);
  unsigned short* wrecB = (unsigned short*)(ws + (size_t)Tn*Bn*Hn*2 + 65536);

  xproj_kernel<<<Tn, 256, 0, stream>>>(inp, wi, brec, xp);
  wrec_pack  <<<128, 256, 0, stream>>>(wrec, wrecB);
  rnn_scan   <<<4, 512, 0, stream>>>(h0, xp, wrecB, hs);
  out_gemm   <<<(Bn*Tn)/64, 256, 0, stream>>>(hs, wo, out);
}

// Round 10
// 2867.474 us; speedup vs baseline: 1.2817x; 1.2817x over previous
//
#include <hip/hip_runtime.h>

#define Tn 1024
#define Bn 64
#define In_ 64
#define Hn 512
#define On 64
#define DTC 0.5f

typedef __attribute__((ext_vector_type(8))) short short8;   // bf16x8 MFMA frag
typedef __attribute__((ext_vector_type(4))) float floatx4;  // MFMA C frag
typedef unsigned long long u64;

__device__ __forceinline__ float bf2f(unsigned short u){
  union{unsigned int i; float f;} v; v.i = ((unsigned int)u)<<16; return v.f;
}
__device__ __forceinline__ unsigned short f2bf(float f){   // RNE
  union{float f; unsigned int i;} v; v.f=f;
  unsigned int x=v.i;
  return (unsigned short)((x + 0x7fffu + ((x>>16)&1u))>>16);
}
__device__ __forceinline__ short8 cvt8(const float* p){
  short8 v;
  #pragma unroll
  for (int e=0;e<8;e++) v[e] = (short)f2bf(p[e]);
  return v;
}
__device__ __forceinline__ unsigned int cvtpk_bf16(float a, float b){
  unsigned int r;  // dst.lo = bf16(a), dst.hi = bf16(b), RNE
  asm("v_cvt_pk_bf16_f32 %0, %1, %2" : "=v"(r) : "v"(a), "v"(b));
  return r;
}
__device__ __forceinline__ float fast_rcp(float x){         // v_rcp_f32
  float r; asm("v_rcp_f32 %0, %1" : "=v"(r) : "v"(x)); return r;
}
// raw LDS-only barrier: no vmcnt(0) drain — global loads/stores keep flying
// across it (this is what makes cross-step VMEM prefetch legal and useful).
__device__ __forceinline__ void barrier_lds(){
  asm volatile("s_waitcnt lgkmcnt(0)\n\ts_barrier" ::: "memory");
}

// ---------------- xproj: xp[t][b][j] = inp[b][t][:]@wi[:,j] + brec[j] (bf16) --------
__global__ __launch_bounds__(256,2) void xproj_kernel(
    const float* __restrict__ inp, const float* __restrict__ wi,
    const float* __restrict__ brec, unsigned short* __restrict__ xp)
{
  const int t = blockIdx.x, tid = threadIdx.x;
  const int wv = tid>>6, lane = tid&63, col = lane&15, quad = lane>>4;
  __shared__ __align__(16) unsigned short inA[64*80];   // [b][i], pad 80
  {
    int r = tid>>2, i0 = (tid&3)*16;
    const float* src = inp + ((size_t)r*Tn + t)*In_ + i0;
    unsigned short tmp[16];
    #pragma unroll
    for (int q=0;q<16;q++) tmp[q] = f2bf(src[q]);
    *(short8*)&inA[r*80 + i0]     = *(short8*)&tmp[0];
    *(short8*)&inA[r*80 + i0 + 8] = *(short8*)&tmp[8];
  }
  const int wnb = wv*128;
  short8 bw[8][2];
  float brecv[8];
  #pragma unroll
  for (int nt=0;nt<8;nt++){
    int j = wnb + nt*16 + col;
    brecv[nt] = brec[j];
    #pragma unroll
    for (int ks=0;ks<2;ks++){
      float tmp[8];
      #pragma unroll
      for (int e=0;e<8;e++) tmp[e] = wi[(size_t)(ks*32 + quad*8 + e)*Hn + j];
      bw[nt][ks] = cvt8(tmp);
    }
  }
  __syncthreads();
  floatx4 acc[4][8];
  #pragma unroll
  for (int mt=0;mt<4;mt++)
    #pragma unroll
    for (int nt=0;nt<8;nt++) acc[mt][nt] = (floatx4){0.f,0.f,0.f,0.f};
  #pragma unroll
  for (int ks=0;ks<2;ks++)
    #pragma unroll
    for (int mt=0;mt<4;mt++){
      short8 ar = *(const short8*)&inA[(mt*16+col)*80 + ks*32 + quad*8];
      #pragma unroll
      for (int nt=0;nt<8;nt++)
        acc[mt][nt] = __builtin_amdgcn_mfma_f32_16x16x32_bf16(ar, bw[nt][ks], acc[mt][nt],0,0,0);
    }
  #pragma unroll
  for (int mt=0;mt<4;mt++)
    #pragma unroll
    for (int nt=0;nt<8;nt++)
      #pragma unroll
      for (int r=0;r<4;r++){
        int b = mt*16 + quad*4 + r;
        int j = wnb + nt*16 + col;
        xp[((size_t)t*Bn + b)*Hn + j] = f2bf(acc[mt][nt][r] + brecv[nt]);
      }
}

// ------------- wrec_pack: bf16 A-frags, layout [ks][jt] (512KB) ---------------------
// frag fi = ks*32+jt (ks=k-slice 0..15, jt=j-tile 0..31); lane l holds
// wrec[jt*16 + (l&15)][ks*32 + (l>>4)*8 + e], e=0..7  -> wrecB[(fi*64+l)*8 + e]
__global__ __launch_bounds__(256,1) void wrec_pack(
    const float* __restrict__ wrec, unsigned short* __restrict__ wrecB)
{
  int gl = blockIdx.x*256 + threadIdx.x;      // 0..32767
  int fi = gl>>6, lane = gl&63;
  int ks = fi>>5, jt = fi&31;
  int j = jt*16 + (lane&15);
  int k = ks*32 + (lane>>4)*8;
  short8 v = cvt8(wrec + (size_t)j*Hn + k);
  *(short8*)(wrecB + (size_t)gl*8) = v;
}

// ------------- scan: 4 blocks x 512 threads (8 waves = 2/SIMD) ----------------------
// pre^T[j][b] = sum_k wrec[j][k] h[b][k].  Wave wv owns j in [64wv,64wv+64) (mt=0..3).
// = r7 (best, 2740us) with ONE change: the K-sweep runs in 2-slice SUPERBLOCKS
// (2 hb ds_reads -> 8 MFMAs) instead of 16x {1 read -> 4 MFMAs}.  r7 counters
// showed MFMA-busy (3170cy) + LDS-busy (3270cy) ~= step (6400cy): the two pipes
// were time-disjoint, waves phase-locked at the 78cy block cadence with 16
// lgkm wait-points each.  Superblocks halve wait-points and double MFMA run
// length (156cy), so the SIMD-partner wave's runs cover the gaps.
// Slice plan (unchanged): ks0..5 reg | ks6..9 LDS (128KB) | ks10..15 streamed
// (10,11 cross-step persistent; 12..15 via two rotating bufs).  hA dbuf 32KB,
// one LDS-only barrier/step.  No sched_barrier/setprio: compiler schedules.
__global__ __launch_bounds__(512,2) void rnn_scan(
    const float* __restrict__ h0,
    const unsigned short* xp,            // ws+64KB  [T][B][H] bf16 (aliases hs+1 slot)
    const unsigned short* __restrict__ wrecB,
    unsigned short* hs)                  // ws       [T][B][H] bf16
{
  const int tid  = threadIdx.x;
  const int g    = blockIdx.x;          // batch group: b in [16g, 16g+16)
  const int wv   = tid >> 6;            // 0..7
  const int lane = tid & 63;
  const int col  = lane & 15;
  const int quad = lane >> 4;
  const int wbase = wv*64;

  __shared__ __align__(16) unsigned short wrecL[4*32*512]; // 128KB: slices 6..9
  __shared__ __align__(16) unsigned short hA[2*8192];      // 32KB: h frags, dbuf

  // frag (ks, jt=wv*4+mt) lives at wrecB[((ks*32 + wv*4 + mt)*64 + lane)*8]
  const unsigned short* pw = wrecB + ((size_t)(wv*4)*64 + lane)*8;
  #define WOFF(ks,mt) ((size_t)((ks)*32 + (mt))*512)

  // A-frags ks 0..5, register-resident (accum side)
  short8 awr[4][6];
  #pragma unroll
  for (int mt=0;mt<4;mt++)
    #pragma unroll
    for (int ks=0;ks<6;ks++)
      awr[mt][ks] = *(const short8*)(pw + WOFF(ks,mt));

  // A-frags ks 6..9 -> LDS; frag (jt=wv*4+mt, s) at ((wv*4+mt)*4+s)*512 shorts
  #pragma unroll
  for (int s=0;s<4;s++)
    #pragma unroll
    for (int mt=0;mt<4;mt++)
      *(short8*)&wrecL[((wv*4+mt)*4+s)*512 + lane*8] =
          *(const short8*)(pw + WOFF(6+s,mt));
  const unsigned short* wl = wrecL + (wv*16)*512 + lane*8;  // + (mt*4+s)*512 imm

  // h0 -> hA buffer 0 (frag layout: (b,k) at ((k>>5)*64+((k>>3)&3)*16+b)*8+(k&7))
  for (int idx = tid; idx < 16*Hn; idx += 512){
    int b = idx >> 9, k = idx & 511;
    hA[(((k>>5)*64 + ((k>>3)&3)*16 + b))*8 + (k&7)] = f2bf(h0[k]);
  }
  // fp32 h master: lane owns (b=col, j = wbase+mt*16+quad*4+r)
  float hm[4][4];
  #pragma unroll
  for (int mt=0;mt<4;mt++)
    #pragma unroll
    for (int r=0;r<4;r++) hm[mt][r] = h0[wbase + mt*16 + quad*4 + r];

  floatx4 acc[4];
  #pragma unroll
  for (int mt=0;mt<4;mt++) acc[mt] = (floatx4){0.f,0.f,0.f,0.f};

  // loop-invariant offsets
  const int row = g*16 + col;           // global batch for this lane
  int xoff[4], woff[4];
  #pragma unroll
  for (int mt=0;mt<4;mt++){
    int j4 = wbase + mt*16 + quad*4;
    xoff[mt] = row*Hn + j4;
    woff[mt] = (((j4>>5)*64 + ((j4>>3)&3)*16 + col))*8 + (j4&7);
  }
  const unsigned short* xq = xp;        // uniform, bumped per step (SGPR)
  unsigned short* hq = hs;
  int hoff = 0;

  __syncthreads();

  #define MFMA4R(KS, HB) { \
    _Pragma("unroll") \
    for (int mt=0;mt<4;mt++) \
      acc[mt] = __builtin_amdgcn_mfma_f32_16x16x32_bf16(awr[mt][KS], (HB), acc[mt],0,0,0); }
  #define MFMA4W(W, HB) { \
    _Pragma("unroll") \
    for (int mt=0;mt<4;mt++) \
      acc[mt] = __builtin_amdgcn_mfma_f32_16x16x32_bf16((W)[mt], (HB), acc[mt],0,0,0); }
  #define MFMA4L(S, HB) { \
    _Pragma("unroll") \
    for (int mt=0;mt<4;mt++){ \
      short8 aw = *(const short8*)(wl + (mt*4+(S))*512); \
      acc[mt] = __builtin_amdgcn_mfma_f32_16x16x32_bf16(aw, (HB), acc[mt],0,0,0); } }
  #define LOADW(W, KS) { \
    _Pragma("unroll") \
    for (int mt=0;mt<4;mt++) (W)[mt] = *(const short8*)(pw + WOFF(KS,mt)); }
  #define RDHB(S) (*(const short8*)(hc + (S)*512))

  // cross-step prefetch of streamed slices 10,11 (wrec is step-invariant)
  short8 wstP0[4], wstP1[4], wstA[4], wstB[4];
  LOADW(wstP0, 10); LOADW(wstP1, 11);

  for (int t = 0; t < Tn; t++){
    // step-top: xproj loads (consumed in epilogue) + mid-sweep streams 12,13
    u64 xv[4];
    #pragma unroll
    for (int mt=0;mt<4;mt++) xv[mt] = *(const u64*)(xq + xoff[mt]);
    LOADW(wstA, 12); LOADW(wstB, 13);

    const unsigned short* hc = hA + hoff + lane*8;

    // ---- K-sweep in 2-slice superblocks: 2 hb reads -> 8 MFMAs ----
    { short8 h0_ = RDHB(0),  h1_ = RDHB(1);                          // P0: ks0,1 (reg)
      MFMA4R(0, h0_); MFMA4R(1, h1_); }
    { short8 h0_ = RDHB(2),  h1_ = RDHB(3);                          // P1: ks2,3 (reg)
      MFMA4R(2, h0_); MFMA4R(3, h1_); }
    { short8 h0_ = RDHB(4),  h1_ = RDHB(5);                          // P2: ks4,5 (reg)
      MFMA4R(4, h0_); MFMA4R(5, h1_); }
    { short8 h0_ = RDHB(12), h1_ = RDHB(13);                         // P3: ks12,13 (str)
      MFMA4W(wstA, h0_); MFMA4W(wstB, h1_); }
    LOADW(wstA, 14); LOADW(wstB, 15);                                //   -> ks14,15
    { short8 h0_ = RDHB(10), h1_ = RDHB(11);                         // P4: ks10,11 (str)
      MFMA4W(wstP0, h0_); MFMA4W(wstP1, h1_); }
    LOADW(wstP0, 10); LOADW(wstP1, 11);                              //   -> t+1
    { short8 h0_ = RDHB(6),  h1_ = RDHB(7);                          // P5: ks6,7 (LDS)
      MFMA4L(0, h0_); MFMA4L(1, h1_); }
    { short8 h0_ = RDHB(14), h1_ = RDHB(15);                         // P6: ks14,15 (str)
      MFMA4W(wstA, h0_); MFMA4W(wstB, h1_); }
    { short8 h0_ = RDHB(8),  h1_ = RDHB(9);                          // P7: ks8,9 (LDS)
      MFMA4L(2, h0_); MFMA4L(3, h1_); }

    // epilogue: writes go to the OTHER hA buffer -> no pre-barrier needed.
    // tanh(pre) = 1 - 2/(e^{2pre}+1); hn = fma(.5,hm,.5) - rcp(e+1)
    unsigned short* hw = hA + (hoff ^ 8192);
    #pragma unroll
    for (int mt=0;mt<4;mt++){
      u64 x = xv[mt];
      float hn[4];
      #pragma unroll
      for (int r=0;r<4;r++){
        float pre = acc[mt][r] + bf2f((unsigned short)(x >> (16*r)));
        float e   = __expf(2.0f*pre);                  // v_mul + v_exp
        float rc  = fast_rcp(e + 1.0f);                // v_add + v_rcp
        float v   = __builtin_fmaf(0.5f, hm[mt][r], 0.5f) - rc;
        hm[mt][r] = v;
        hn[r] = v;
      }
      unsigned int lo = cvtpk_bf16(hn[0], hn[1]);
      unsigned int hi = cvtpk_bf16(hn[2], hn[3]);
      uint2 w; w.x = lo; w.y = hi;
      *(uint2*)&hw[woff[mt]] = w;                      // ds_write_b64, frag layout
      u64 pk = (u64)lo | ((u64)hi << 32);
      __builtin_nontemporal_store(pk, (u64*)(hq + xoff[mt]));   // hs[t][b][j4..j4+3]
      acc[mt] = (floatx4){0.f,0.f,0.f,0.f};
    }
    barrier_lds();     // LDS ops drained CU-wide; prefetched VMEM keeps flying
    hoff ^= 8192;
    xq += Bn*Hn;
    hq += Bn*Hn;
  }
  #undef MFMA4R
  #undef MFMA4W
  #undef MFMA4L
  #undef LOADW
  #undef RDHB
  #undef WOFF
}

// ------------- out: out[b][t][o] = hs[t][b][:] @ wo ; rows m = t*64+b ---------------
__global__ __launch_bounds__(256,1) void out_gemm(
    const unsigned short* __restrict__ hs,
    const float* __restrict__ wo,
    float* __restrict__ out)
{
  const int tid = threadIdx.x, bid = blockIdx.x;
  const int wv = tid >> 6, lane = tid & 63, col = lane & 15, quad = lane >> 4;
  const int m0 = bid*64;
  __shared__ __align__(16) unsigned short hsA[64][520];

  for (int c = tid; c < 64*64; c += 256){
    int r = c >> 6, cc = (c & 63)*8;
    *(short8*)&hsA[r][cc] = *(const short8*)(hs + (size_t)(m0 + r)*Hn + cc);
  }
  short8 boh[16], bol[16];
  #pragma unroll
  for (int kk = 0; kk < 16; kk++){
    float tmp[8];
    #pragma unroll
    for (int e = 0; e < 8; e++) tmp[e] = wo[(size_t)(kk*32 + quad*8 + e)*On + wv*16 + col];
    #pragma unroll
    for (int e = 0; e < 8; e++){
      unsigned short h = f2bf(tmp[e]);
      boh[kk][e] = (short)h;
      bol[kk][e] = (short)f2bf(tmp[e] - bf2f(h));
    }
  }
  __syncthreads();

  floatx4 acc[4];
  #pragma unroll
  for (int ms=0;ms<4;ms++) acc[ms] = (floatx4){0.f,0.f,0.f,0.f};
  #pragma unroll
  for (int kk = 0; kk < 16; kk++){
    int k = kk*32 + quad*8;
    #pragma unroll
    for (int ms = 0; ms < 4; ms++){
      short8 a = *(const short8*)&hsA[ms*16 + col][k];
      acc[ms] = __builtin_amdgcn_mfma_f32_16x16x32_bf16(a, boh[kk], acc[ms], 0,0,0);
      acc[ms] = __builtin_amdgcn_mfma_f32_16x16x32_bf16(a, bol[kk], acc[ms], 0,0,0);
    }
  }
  #pragma unroll
  for (int ms = 0; ms < 4; ms++)
    #pragma unroll
    for (int r = 0; r < 4; r++){
      int m = m0 + ms*16 + quad*4 + r;     // m = t*64 + b
      int b = m & 63, tt = m >> 6;
      out[((size_t)b*Tn + tt)*On + wv*16 + col] = acc[ms][r];
    }
}

extern "C" void kernel_launch(void* const* d_in, const int* in_sizes, int n_in,
                              void* d_out, int out_size, void* d_ws, size_t ws_size,
                              hipStream_t stream){
  const float* inp  = (const float*)d_in[0];
  const float* wi   = (const float*)d_in[1];
  const float* wrec = (const float*)d_in[2];
  const float* wo   = (const float*)d_in[3];
  const float* brec = (const float*)d_in[4];
  const float* h0   = (const float*)d_in[5];
  float* out = (float*)d_out;

  char* ws = (char*)d_ws;
  // hs slots: ws + t*64KB. xp slots: ws + 64KB + t*64KB (= hs slot t+1).
  // Scan step t writes hs[t] (destroys xp[t-1], already consumed; per-group
  // b-slices disjoint, so cross-block skew is safe). wrecB (512KB packed
  // bf16 frags, [ks][jt] order) lives past the last xp slot.
  unsigned short* hs = (unsigned short*)ws;
  unsigned short* xp = (unsigned short*)(ws + 65536);
  unsigned short* wrecB = (unsigned short*)(ws + (size_t)Tn*Bn*Hn*2 + 65536);

  xproj_kernel<<<Tn, 256, 0, stream>>>(inp, wi, brec, xp);
  wrec_pack  <<<128, 256, 0, stream>>>(wrec, wrecB);
  rnn_scan   <<<4, 512, 0, stream>>>(h0, xp, wrecB, hs);
  out_gemm   <<<(Bn*Tn)/64, 256, 0, stream>>>(hs, wo, out);
}